// Round 1
// baseline (5968.257 us; speedup 1.0000x reference)
//
#include <hip/hip_runtime.h>

// Generator_78683800862785: attention+LSTM decoder, BS=1024, T=30.
// Strategy: fp16 MFMA GEMMs w/ fp32 accum; K/V never materialized (folded into
// C = scale*K_w^T Q_w acting on encoded); att->out->fc1 folded into Wfc1.
// All activations fp16, cell states fp32. ~220 launches/call.

#define DEVI __device__ __forceinline__

typedef _Float16 f16x8 __attribute__((ext_vector_type(8)));
typedef _Float16 f16x4 __attribute__((ext_vector_type(4)));
typedef float    f32x4 __attribute__((ext_vector_type(4)));

#define BSZ 1024
#define SEQ 100
#define ENC 256
#define HID 512
#define LAT 64
#define TT  30

// ---------------------------------------------------------------- utilities
DEVI float lrelu(float v) { return v >= 0.f ? v : 0.2f * v; }
DEVI float sigm(float x)  { return 1.f / (1.f + __expf(-x)); }
DEVI float tanh_f(float x){ return 1.f - 2.f / (1.f + __expf(2.f * x)); }

// ---------------------------------------------------------------- setup kernels
__global__ __launch_bounds__(256) void zero_ws(uint4* __restrict__ p) {
    uint4 z; z.x = z.y = z.z = z.w = 0u;
    p[(size_t)blockIdx.x * 256 + threadIdx.x] = z;
}

// encoded fp32 -> fp16  (26,214,400 elems / 4 per thread; grid 25600)
__global__ __launch_bounds__(256) void conv_enc(const float4* __restrict__ src,
                                                f16x4* __restrict__ dst) {
    size_t i = (size_t)blockIdx.x * 256 + threadIdx.x;
    float4 v = src[i];
    f16x4 h;
    h.x = (_Float16)v.x; h.y = (_Float16)v.y; h.z = (_Float16)v.z; h.w = (_Float16)v.w;
    dst[i] = h;
}

// C[ne,h] = scale * sum_d k_w[n*128+d, e] * q_w[n*128+d, h]   (fp16 out)
// d[ne]   = scale * sum_d k_w[n*128+d, e] * q_b[n*128+d]
__global__ __launch_bounds__(256) void prep_qk(const float* __restrict__ k_w,
                                               const float* __restrict__ q_w,
                                               const float* __restrict__ q_b,
                                               _Float16* __restrict__ C_h,
                                               float* __restrict__ d_f,
                                               _Float16* __restrict__ d_h) {
    const int ne = blockIdx.x, n = ne >> 8, e = ne & 255, tid = threadIdx.x;
    const float scale = 0.08838834764831845f;  // 1/sqrt(128)
    float a0 = 0.f, a1 = 0.f;
    for (int dd = 0; dd < 128; ++dd) {
        float kv = k_w[(n * 128 + dd) * 256 + e];
        a0 += kv * q_w[(n * 128 + dd) * 512 + tid];
        a1 += kv * q_w[(n * 128 + dd) * 512 + 256 + tid];
    }
    C_h[(size_t)ne * 512 + tid]       = (_Float16)(scale * a0);
    C_h[(size_t)ne * 512 + 256 + tid] = (_Float16)(scale * a1);
    float pq = (tid < 128) ? k_w[(n * 128 + tid) * 256 + e] * q_b[n * 128 + tid] : 0.f;
    #pragma unroll
    for (int off = 32; off; off >>= 1) pq += __shfl_down(pq, off);
    __shared__ float red[4];
    if ((tid & 63) == 0) red[tid >> 6] = pq;
    __syncthreads();
    if (tid == 0) {
        float s = scale * (red[0] + red[1] + red[2] + red[3]);
        d_f[ne] = s; d_h[ne] = (_Float16)s;
    }
}

// A[h,k] = sum_m fc1_w[h, m] * out_w[m, k]   (fp32, m<512; fc1_w row len 576)
__global__ __launch_bounds__(256) void prep_A(const float* __restrict__ fc1_w,
                                              const float* __restrict__ out_w,
                                              float* __restrict__ A) {
    const int h = blockIdx.x, tid = threadIdx.x;
    float a0 = 0.f, a1 = 0.f;
    for (int m = 0; m < 512; ++m) {
        float fv = fc1_w[h * 576 + m];
        a0 += fv * out_w[m * 512 + tid];
        a1 += fv * out_w[m * 512 + 256 + tid];
    }
    A[(size_t)h * 512 + tid]       = a0;
    A[(size_t)h * 512 + 256 + tid] = a1;
}

// Wfc1[h, n*256+e] = sum_d A[h, n*128+d]*v_w[n*128+d, e];  cols 1024..1087 = fc1_w[h,512+l]
// biasf[h] = A[h,:]·v_b + fc1_w[h,:512]·out_b + fc1_b[h]
__global__ __launch_bounds__(256) void prep_wfc1(const float* __restrict__ A,
                                                 const float* __restrict__ v_w,
                                                 const float* __restrict__ v_b,
                                                 const float* __restrict__ fc1_w,
                                                 const float* __restrict__ out_b,
                                                 const float* __restrict__ fc1_b,
                                                 _Float16* __restrict__ Wfc1,
                                                 float* __restrict__ biasf) {
    const int h = blockIdx.x, tid = threadIdx.x;
    #pragma unroll
    for (int g = 0; g < 4; ++g) {
        int e = tid;
        float acc = 0.f;
        for (int dd = 0; dd < 128; ++dd)
            acc += A[h * 512 + g * 128 + dd] * v_w[(g * 128 + dd) * 256 + e];
        Wfc1[(size_t)h * 1088 + g * 256 + e] = (_Float16)acc;
    }
    if (tid < 64)
        Wfc1[(size_t)h * 1088 + 1024 + tid] = (_Float16)fc1_w[h * 576 + 512 + tid];
    float ps = A[h * 512 + tid] * v_b[tid] + A[h * 512 + 256 + tid] * v_b[256 + tid]
             + fc1_w[h * 576 + tid] * out_b[tid] + fc1_w[h * 576 + 256 + tid] * out_b[256 + tid];
    #pragma unroll
    for (int off = 32; off; off >>= 1) ps += __shfl_down(ps, off);
    __shared__ float red[4];
    if ((tid & 63) == 0) red[tid >> 6] = ps;
    __syncthreads();
    if (tid == 0) biasf[h] = red[0] + red[1] + red[2] + red[3] + fc1_b[h];
}

// concat [wih | whh] -> fp16 [2048 x 1024]; bias = bih+bhh (fp32). grid 8192.
__global__ __launch_bounds__(256) void prep_lstm(const float* __restrict__ wih,
                                                 const float* __restrict__ whh,
                                                 const float* __restrict__ bih,
                                                 const float* __restrict__ bhh,
                                                 _Float16* __restrict__ Wc,
                                                 float* __restrict__ bc) {
    int idx = blockIdx.x * 256 + threadIdx.x;  // 2,097,152
    int r = idx >> 10, cc = idx & 1023;
    float v = (cc < 512) ? wih[(size_t)r * 512 + cc] : whh[(size_t)r * 512 + cc - 512];
    Wc[idx] = (_Float16)v;
    if (idx < 2048) bc[idx] = bih[idx] + bhh[idx];
}

// fc2 weight transposes -> fp16. grid 641.
__global__ __launch_bounds__(256) void prep_fc2t(const float* __restrict__ aw,
                                                 const float* __restrict__ bw,
                                                 const float* __restrict__ cw,
                                                 _Float16* __restrict__ aT,
                                                 _Float16* __restrict__ bT,
                                                 _Float16* __restrict__ cT) {
    int i = blockIdx.x * 256 + threadIdx.x;
    if (i < 131072) {
        int k = i >> 8, j = i & 255;
        aT[k * 256 + j] = (_Float16)aw[j * 512 + k];
    } else if (i < 131072 + 32768) {
        int i2 = i - 131072, k = i2 >> 7, j = i2 & 127;
        bT[k * 128 + j] = (_Float16)bw[j * 256 + k];
    } else if (i < 131072 + 32768 + 256) {
        int i3 = i - 131072 - 32768, k = i3 >> 1, o = i3 & 1;
        cT[k * 2 + o] = (_Float16)cw[o * 128 + k];
    }
}

// G[b,:] = d  (t=0 state: att_in=0 -> G = bias d). grid 1024.
__global__ __launch_bounds__(256) void bcast_G(const _Float16* __restrict__ d_h,
                                               _Float16* __restrict__ G) {
    const int b = blockIdx.x, tid = threadIdx.x;
    f16x4 v = *(const f16x4*)(d_h + tid * 4);
    *(f16x4*)(G + (size_t)b * 1024 + tid * 4) = v;
}

// ---------------------------------------------------------------- GEMM (fp16 MFMA)
// out[b,j] = act( sum_k X[b,k]*W[j,k] + bias[j] ), W row-major [N,K].
// A-frag: A[m=lane&15][k=(lane>>4)*8+j]; B-frag: B[k][n=lane&15]; D: row=(lane>>4)*4+r, col=lane&15.
template <int BM, int BN, int WM, int WN, int ACT, bool HASBIAS>
DEVI void gemm_body(_Float16* __restrict__ smem,
                    const _Float16* __restrict__ X, int ldx,
                    const _Float16* __restrict__ W,
                    const float* __restrict__ bias,
                    _Float16* __restrict__ out, int ldo,
                    int K, int bx, int by) {
    constexpr int BK = 32;
    constexpr int LDT = BK + 8;  // +8 halves pad: b128 frag reads <=2-way conflict (free)
    _Float16* Xs = smem;
    _Float16* Ws = smem + BM * LDT;
    const int tid = threadIdx.x;
    const int wave = tid >> 6, lane = tid & 63;
    constexpr int WROWS = BM / WM;
    const int wm = wave % WROWS, wn = wave / WROWS;
    const int bm0 = by * BM, bn0 = bx * BN;
    constexpr int MT = WM / 16, NT = WN / 16;
    f32x4 acc[MT][NT] = {};
    const int q = lane >> 4, m15 = lane & 15;
    const int srow = tid >> 2, sch = (tid & 3) * 8;

    for (int k0 = 0; k0 < K; k0 += BK) {
        #pragma unroll
        for (int c = 0; c < BM / 64; ++c) {
            int row = srow + c * 64;
            *(uint4*)&Xs[row * LDT + sch] =
                *(const uint4*)&X[(size_t)(bm0 + row) * ldx + k0 + sch];
        }
        #pragma unroll
        for (int c = 0; c < BN / 64; ++c) {
            int row = srow + c * 64;
            *(uint4*)&Ws[row * LDT + sch] =
                *(const uint4*)&W[(size_t)(bn0 + row) * K + k0 + sch];
        }
        __syncthreads();
        f16x8 af[MT], bf[NT];
        #pragma unroll
        for (int i = 0; i < MT; ++i)
            af[i] = *(const f16x8*)&Xs[(wm * WM + i * 16 + m15) * LDT + q * 8];
        #pragma unroll
        for (int j = 0; j < NT; ++j)
            bf[j] = *(const f16x8*)&Ws[(wn * WN + j * 16 + m15) * LDT + q * 8];
        #pragma unroll
        for (int i = 0; i < MT; ++i)
            #pragma unroll
            for (int j = 0; j < NT; ++j)
                acc[i][j] = __builtin_amdgcn_mfma_f32_16x16x32_f16(af[i], bf[j], acc[i][j], 0, 0, 0);
        __syncthreads();
    }
    #pragma unroll
    for (int i = 0; i < MT; ++i) {
        #pragma unroll
        for (int j = 0; j < NT; ++j) {
            int col = bn0 + wn * WN + j * 16 + m15;
            float bv = HASBIAS ? bias[col] : 0.f;
            #pragma unroll
            for (int r = 0; r < 4; ++r) {
                int rowg = bm0 + wm * WM + i * 16 + q * 4 + r;
                float v = acc[i][j][r] + bv;
                if (ACT == 1) v = lrelu(v);
                out[(size_t)rowg * ldo + col] = (_Float16)v;
            }
        }
    }
}

template <int BM, int BN, int WM, int WN, int ACT, bool HASBIAS>
__global__ __launch_bounds__(256) void gemm_k(const _Float16* __restrict__ X, int ldx,
                                              const _Float16* __restrict__ W,
                                              const float* __restrict__ bias,
                                              _Float16* __restrict__ out, int ldo, int K) {
    __shared__ _Float16 smem[(BM + BN) * 40];
    gemm_body<BM, BN, WM, WN, ACT, HASBIAS>(smem, X, ldx, W, bias, out, ldo, K,
                                            blockIdx.x, blockIdx.y);
}

// ---------------------------------------------------------------- attention step
// scores(b,n,s) = G[b,n*256:]·enc[b,s,:]; softmax over s; eb[b,n*256+e] = sum_s w*enc.
// Also copies z_t (fp32->fp16) into eb cols 1024..1087. grid 1024 (one block per b).
__global__ __launch_bounds__(256) void attn_step(const _Float16* __restrict__ G,
                                                 const _Float16* __restrict__ encH,
                                                 const float* __restrict__ z,
                                                 _Float16* __restrict__ eb, int t) {
    const int b = blockIdx.x, tid = threadIdx.x;
    const int wave = tid >> 6, lane = tid & 63;
    __shared__ float sc[4][128];
    __shared__ float wsm[4][128];
    const _Float16* ep = encH + (size_t)b * SEQ * ENC;
    {   // phase 1: scores, one head per wave
        f16x4 g4 = *(const f16x4*)(G + (size_t)b * 1024 + wave * ENC + lane * 4);
        float g0 = (float)g4.x, g1 = (float)g4.y, g2 = (float)g4.z, g3 = (float)g4.w;
        for (int s = 0; s < SEQ; ++s) {
            f16x4 e4 = *(const f16x4*)(ep + s * ENC + lane * 4);
            float p = g0 * (float)e4.x + g1 * (float)e4.y + g2 * (float)e4.z + g3 * (float)e4.w;
            #pragma unroll
            for (int off = 32; off; off >>= 1) p += __shfl_down(p, off);
            if (lane == 0) sc[wave][s] = p;
        }
    }
    __syncthreads();
    {   // phase 2: softmax per head (wave handles own row)
        float v0 = sc[wave][lane];
        float v1 = (lane < SEQ - 64) ? sc[wave][64 + lane] : -1e30f;
        float m = fmaxf(v0, v1);
        #pragma unroll
        for (int off = 32; off; off >>= 1) m = fmaxf(m, __shfl_xor(m, off));
        float e0 = __expf(v0 - m);
        float e1 = (lane < SEQ - 64) ? __expf(v1 - m) : 0.f;
        float ss = e0 + e1;
        #pragma unroll
        for (int off = 32; off; off >>= 1) ss += __shfl_xor(ss, off);
        float inv = 1.f / ss;
        wsm[wave][lane] = e0 * inv;
        if (lane < SEQ - 64) wsm[wave][64 + lane] = e1 * inv;
    }
    __syncthreads();
    {   // phase 3: weighted sum of encoded rows
        const int e0 = lane * 4;
        float a0 = 0.f, a1 = 0.f, a2 = 0.f, a3 = 0.f;
        for (int s = 0; s < SEQ; ++s) {
            f16x4 e4 = *(const f16x4*)(ep + s * ENC + e0);
            float w = wsm[wave][s];
            a0 += w * (float)e4.x; a1 += w * (float)e4.y;
            a2 += w * (float)e4.z; a3 += w * (float)e4.w;
        }
        f16x4 r;
        r.x = (_Float16)a0; r.y = (_Float16)a1; r.z = (_Float16)a2; r.w = (_Float16)a3;
        *(f16x4*)(eb + (size_t)b * 1088 + wave * ENC + e0) = r;
    }
    if (tid < LAT)
        eb[(size_t)b * 1088 + 1024 + tid] = (_Float16)z[((size_t)b * TT + t) * LAT + tid];
}

// ---------------------------------------------------------------- LSTM elementwise
__global__ __launch_bounds__(256) void lstm_ew(const _Float16* __restrict__ gates,
                                               float* __restrict__ c,
                                               _Float16* __restrict__ ha,
                                               _Float16* __restrict__ hb) {
    int gid = blockIdx.x * 256 + threadIdx.x;  // 524288
    int b = gid >> 9, h = gid & 511;
    const _Float16* g = gates + (size_t)b * 2048;
    float gi = (float)g[h], gf = (float)g[512 + h], gg = (float)g[1024 + h], go = (float)g[1536 + h];
    float cn = sigm(gf) * c[gid] + sigm(gi) * tanh_f(gg);
    c[gid] = cn;
    _Float16 hn = (_Float16)(sigm(go) * tanh_f(cn));
    ha[(size_t)b * 1024 + h] = hn;
    if (hb) hb[(size_t)b * 1024 + h] = hn;
}

// ---------------------------------------------------------------- fc2 chain (+ fused next-step q GEMM)
__device__ void fc2_body(_Float16* smem, const _Float16* __restrict__ xh2,
                         const _Float16* __restrict__ aT, const float* __restrict__ ab,
                         const _Float16* __restrict__ bT, const float* __restrict__ bb,
                         const _Float16* __restrict__ cT, const float* __restrict__ cb,
                         float* __restrict__ out, int b0, int t) {
    _Float16* h2s = smem;          // 4*512
    _Float16* y1s = smem + 2048;   // 4*256
    _Float16* y2s = smem + 3072;   // 4*128
    const int tid = threadIdx.x;
    {
        int r = tid >> 6, k = (tid & 63) * 8;
        *(uint4*)&h2s[r * 512 + k] = *(const uint4*)&xh2[(size_t)(b0 + r) * 1024 + 512 + k];
    }
    __syncthreads();
    {
        float a0 = 0.f, a1 = 0.f, a2 = 0.f, a3 = 0.f;
        for (int k = 0; k < 512; ++k) {
            float w = (float)aT[k * 256 + tid];
            a0 += w * (float)h2s[k];        a1 += w * (float)h2s[512 + k];
            a2 += w * (float)h2s[1024 + k]; a3 += w * (float)h2s[1536 + k];
        }
        float bj = ab[tid];
        y1s[tid]       = (_Float16)lrelu(a0 + bj);
        y1s[256 + tid] = (_Float16)lrelu(a1 + bj);
        y1s[512 + tid] = (_Float16)lrelu(a2 + bj);
        y1s[768 + tid] = (_Float16)lrelu(a3 + bj);
    }
    __syncthreads();
    if (tid < 128) {
        float a0 = 0.f, a1 = 0.f, a2 = 0.f, a3 = 0.f;
        for (int k = 0; k < 256; ++k) {
            float w = (float)bT[k * 128 + tid];
            a0 += w * (float)y1s[k];       a1 += w * (float)y1s[256 + k];
            a2 += w * (float)y1s[512 + k]; a3 += w * (float)y1s[768 + k];
        }
        float bj = bb[tid];
        y2s[tid]       = (_Float16)lrelu(a0 + bj);
        y2s[128 + tid] = (_Float16)lrelu(a1 + bj);
        y2s[256 + tid] = (_Float16)lrelu(a2 + bj);
        y2s[384 + tid] = (_Float16)lrelu(a3 + bj);
    }
    __syncthreads();
    if (tid < 8) {
        int r = tid >> 1, o = tid & 1;
        float acc = cb[o];
        for (int k = 0; k < 128; ++k) acc += (float)cT[k * 2 + o] * (float)y2s[r * 128 + k];
        out[((size_t)(b0 + r) * TT + t) * 2 + o] = tanhf(acc);
    }
}

// blocks 0..255: G(t+1) = h2 @ C^T + d ; blocks 256..511: fc2 output for step t.
__global__ __launch_bounds__(256) void out_and_q(const _Float16* __restrict__ xh2,
                                                 const _Float16* __restrict__ C_h,
                                                 const float* __restrict__ d_f,
                                                 _Float16* __restrict__ G,
                                                 const _Float16* __restrict__ aT, const float* __restrict__ ab,
                                                 const _Float16* __restrict__ bT, const float* __restrict__ bb,
                                                 const _Float16* __restrict__ cT, const float* __restrict__ cb,
                                                 float* __restrict__ out, int t, int do_gemm) {
    __shared__ _Float16 smem[(64 + 64) * 40];
    if (blockIdx.x < 256) {
        if (!do_gemm) return;
        gemm_body<64, 64, 32, 32, 0, true>(smem, xh2 + 512, 1024, C_h, d_f, G, 1024, 512,
                                           blockIdx.x & 15, blockIdx.x >> 4);
    } else {
        fc2_body(smem, xh2, aT, ab, bT, bb, cT, cb, out, (blockIdx.x - 256) * 4, t);
    }
}

// ---------------------------------------------------------------- launch
extern "C" void kernel_launch(void* const* d_in, const int* in_sizes, int n_in,
                              void* d_out, int out_size, void* d_ws, size_t ws_size,
                              hipStream_t stream) {
    const float* encoded = (const float*)d_in[0];
    const float* z       = (const float*)d_in[1];
    const float* q_w     = (const float*)d_in[2];
    const float* k_w     = (const float*)d_in[3];
    const float* v_w     = (const float*)d_in[4];
    const float* q_b     = (const float*)d_in[5];
    // d_in[6] (k_b): contributes only softmax-invariant constants — dropped exactly.
    const float* v_b     = (const float*)d_in[7];
    const float* out_w   = (const float*)d_in[8];
    const float* out_b   = (const float*)d_in[9];
    const float* fc1_w   = (const float*)d_in[10];
    const float* fc1_b   = (const float*)d_in[11];
    const float* l1_wih  = (const float*)d_in[12];
    const float* l1_whh  = (const float*)d_in[13];
    const float* l1_bih  = (const float*)d_in[14];
    const float* l1_bhh  = (const float*)d_in[15];
    const float* l2_wih  = (const float*)d_in[16];
    const float* l2_whh  = (const float*)d_in[17];
    const float* l2_bih  = (const float*)d_in[18];
    const float* l2_bhh  = (const float*)d_in[19];
    const float* fc2a_w  = (const float*)d_in[20];
    const float* fc2a_b  = (const float*)d_in[21];
    const float* fc2b_w  = (const float*)d_in[22];
    const float* fc2b_b  = (const float*)d_in[23];
    const float* fc2c_w  = (const float*)d_in[24];
    const float* fc2c_b  = (const float*)d_in[25];
    float* out = (float*)d_out;

    char* p = (char*)d_ws;
    auto take = [&](size_t bytes) { char* r = p; p += (bytes + 255) & ~(size_t)255; return r; };
    _Float16* encH  = (_Float16*)take(52428800);   // [1024,100,256] fp16
    _Float16* C_h   = (_Float16*)take(1048576);    // [1024,512]
    _Float16* Wfc1  = (_Float16*)take(1114112);    // [512,1088]
    _Float16* L1W   = (_Float16*)take(4194304);    // [2048,1024]
    _Float16* L2W   = (_Float16*)take(4194304);
    _Float16* fc2aT = (_Float16*)take(262144);
    _Float16* fc2bT = (_Float16*)take(65536);
    _Float16* fc2cT = (_Float16*)take(512);
    _Float16* gates = (_Float16*)take(4194304);    // [1024,2048]
    _Float16* eb    = (_Float16*)take(2228224);    // [1024,1088]
    char* zreg = p;                                // ---- zero region (10 MB) ----
    _Float16* xh1 = (_Float16*)take(2097152);      // [1024, 1024] = [fc1out | h1]
    _Float16* xh2 = (_Float16*)take(2097152);      // [1024, 1024] = [h1 | h2]
    _Float16* G   = (_Float16*)take(2097152);      // [1024, 1024]
    float* c1     = (float*)take(2097152);
    float* c2     = (float*)take(2097152);         // ---- end zero region ----
    float* A      = (float*)take(1048576);         // fp32 [512,512]
    float* d_f    = (float*)take(4096);
    _Float16* d_h = (_Float16*)take(2048);
    float* biasf  = (float*)take(2048);
    float* L1b    = (float*)take(8192);
    float* L2b    = (float*)take(8192);
    (void)in_sizes; (void)n_in; (void)out_size; (void)ws_size;

    zero_ws<<<2560, 256, 0, stream>>>((uint4*)zreg);
    conv_enc<<<25600, 256, 0, stream>>>((const float4*)encoded, (f16x4*)encH);
    prep_qk<<<1024, 256, 0, stream>>>(k_w, q_w, q_b, C_h, d_f, d_h);
    prep_A<<<512, 256, 0, stream>>>(fc1_w, out_w, A);
    prep_wfc1<<<512, 256, 0, stream>>>(A, v_w, v_b, fc1_w, out_b, fc1_b, Wfc1, biasf);
    prep_lstm<<<8192, 256, 0, stream>>>(l1_wih, l1_whh, l1_bih, l1_bhh, L1W, L1b);
    prep_lstm<<<8192, 256, 0, stream>>>(l2_wih, l2_whh, l2_bih, l2_bhh, L2W, L2b);
    prep_fc2t<<<641, 256, 0, stream>>>(fc2a_w, fc2b_w, fc2c_w, fc2aT, fc2bT, fc2cT);
    bcast_G<<<1024, 256, 0, stream>>>(d_h, G);

    for (int t = 0; t < TT; ++t) {
        attn_step<<<1024, 256, 0, stream>>>(G, encH, z, eb, t);
        // fc1: [1024,1088] @ [512,1088]^T, lrelu
        gemm_k<64, 64, 32, 32, 1, true><<<dim3(8, 16), 256, 0, stream>>>(
            eb, 1088, Wfc1, biasf, xh1, 1024, 1088);
        // LSTM1 gates: [1024,1024] @ [2048,1024]^T
        gemm_k<128, 64, 32, 64, 0, true><<<dim3(32, 8), 256, 0, stream>>>(
            xh1, 1024, L1W, L1b, gates, 2048, 1024);
        lstm_ew<<<2048, 256, 0, stream>>>(gates, c1, xh1 + 512, xh2);
        // LSTM2 gates
        gemm_k<128, 64, 32, 64, 0, true><<<dim3(32, 8), 256, 0, stream>>>(
            xh2, 1024, L2W, L2b, gates, 2048, 1024);
        lstm_ew<<<2048, 256, 0, stream>>>(gates, c2, xh2 + 512, (_Float16*)nullptr);
        // fc2 output for step t + q-projection GEMM for step t+1 (fused)
        out_and_q<<<512, 256, 0, stream>>>(xh2, C_h, d_f, G,
                                           fc2aT, fc2a_b, fc2bT, fc2b_b, fc2cT, fc2c_b,
                                           out, t, (t < TT - 1) ? 1 : 0);
    }
}

// Round 2
// 4709.378 us; speedup vs baseline: 1.2673x; 1.2673x over previous
//
#include <hip/hip_runtime.h>

// Generator_78683800862785: attention+LSTM decoder, BS=1024, T=30.
// fp16 MFMA GEMMs w/ fp32 accum; K/V folded into C = scale*K_w^T Q_w;
// att->out->fc1 folded into Wfc1; LSTM gate-ew fused into GEMM epilogue
// (weights row-reordered to h*4+gate). 5 launches per step.

#define DEVI __device__ __forceinline__

typedef _Float16 f16x8 __attribute__((ext_vector_type(8)));
typedef _Float16 f16x4 __attribute__((ext_vector_type(4)));
typedef float    f32x4 __attribute__((ext_vector_type(4)));

#define BSZ 1024
#define SEQ 100
#define ENC 256
#define HID 512
#define LAT 64
#define TT  30

// ---------------------------------------------------------------- utilities
DEVI float lrelu(float v) { return v >= 0.f ? v : 0.2f * v; }
DEVI float sigm(float x)  { return 1.f / (1.f + __expf(-x)); }
DEVI float tanh_f(float x){ return 1.f - 2.f / (1.f + __expf(2.f * x)); }

// ---------------------------------------------------------------- setup kernels
__global__ __launch_bounds__(256) void zero_ws(uint4* __restrict__ p) {
    uint4 z; z.x = z.y = z.z = z.w = 0u;
    p[(size_t)blockIdx.x * 256 + threadIdx.x] = z;
}

__global__ __launch_bounds__(256) void conv_enc(const float4* __restrict__ src,
                                                f16x4* __restrict__ dst) {
    size_t i = (size_t)blockIdx.x * 256 + threadIdx.x;
    float4 v = src[i];
    f16x4 h;
    h.x = (_Float16)v.x; h.y = (_Float16)v.y; h.z = (_Float16)v.z; h.w = (_Float16)v.w;
    dst[i] = h;
}

// C[ne,h] = scale * sum_d k_w[n*128+d, e] * q_w[n*128+d, h]   (fp16 out)
// d[ne]   = scale * sum_d k_w[n*128+d, e] * q_b[n*128+d]
__global__ __launch_bounds__(256) void prep_qk(const float* __restrict__ k_w,
                                               const float* __restrict__ q_w,
                                               const float* __restrict__ q_b,
                                               _Float16* __restrict__ C_h,
                                               float* __restrict__ d_f,
                                               _Float16* __restrict__ d_h) {
    const int ne = blockIdx.x, n = ne >> 8, e = ne & 255, tid = threadIdx.x;
    const float scale = 0.08838834764831845f;  // 1/sqrt(128)
    float a0 = 0.f, a1 = 0.f;
    for (int dd = 0; dd < 128; ++dd) {
        float kv = k_w[(n * 128 + dd) * 256 + e];
        a0 += kv * q_w[(n * 128 + dd) * 512 + tid];
        a1 += kv * q_w[(n * 128 + dd) * 512 + 256 + tid];
    }
    C_h[(size_t)ne * 512 + tid]       = (_Float16)(scale * a0);
    C_h[(size_t)ne * 512 + 256 + tid] = (_Float16)(scale * a1);
    float pq = (tid < 128) ? k_w[(n * 128 + tid) * 256 + e] * q_b[n * 128 + tid] : 0.f;
    #pragma unroll
    for (int off = 32; off; off >>= 1) pq += __shfl_down(pq, off);
    __shared__ float red[4];
    if ((tid & 63) == 0) red[tid >> 6] = pq;
    __syncthreads();
    if (tid == 0) {
        float s = scale * (red[0] + red[1] + red[2] + red[3]);
        d_f[ne] = s; d_h[ne] = (_Float16)s;
    }
}

// A[h,k] = sum_m fc1_w[h, m] * out_w[m, k]
__global__ __launch_bounds__(256) void prep_A(const float* __restrict__ fc1_w,
                                              const float* __restrict__ out_w,
                                              float* __restrict__ A) {
    const int h = blockIdx.x, tid = threadIdx.x;
    float a0 = 0.f, a1 = 0.f;
    for (int m = 0; m < 512; ++m) {
        float fv = fc1_w[h * 576 + m];
        a0 += fv * out_w[m * 512 + tid];
        a1 += fv * out_w[m * 512 + 256 + tid];
    }
    A[(size_t)h * 512 + tid]       = a0;
    A[(size_t)h * 512 + 256 + tid] = a1;
}

// Wfc1[h, n*256+e] = sum_d A[h, n*128+d]*v_w[n*128+d, e]; cols 1024..1087 = fc1_w[h,512+l]
__global__ __launch_bounds__(256) void prep_wfc1(const float* __restrict__ A,
                                                 const float* __restrict__ v_w,
                                                 const float* __restrict__ v_b,
                                                 const float* __restrict__ fc1_w,
                                                 const float* __restrict__ out_b,
                                                 const float* __restrict__ fc1_b,
                                                 _Float16* __restrict__ Wfc1,
                                                 float* __restrict__ biasf) {
    const int h = blockIdx.x, tid = threadIdx.x;
    #pragma unroll
    for (int g = 0; g < 4; ++g) {
        float acc = 0.f;
        for (int dd = 0; dd < 128; ++dd)
            acc += A[h * 512 + g * 128 + dd] * v_w[(g * 128 + dd) * 256 + tid];
        Wfc1[(size_t)h * 1088 + g * 256 + tid] = (_Float16)acc;
    }
    if (tid < 64)
        Wfc1[(size_t)h * 1088 + 1024 + tid] = (_Float16)fc1_w[h * 576 + 512 + tid];
    float ps = A[h * 512 + tid] * v_b[tid] + A[h * 512 + 256 + tid] * v_b[256 + tid]
             + fc1_w[h * 576 + tid] * out_b[tid] + fc1_w[h * 576 + 256 + tid] * out_b[256 + tid];
    #pragma unroll
    for (int off = 32; off; off >>= 1) ps += __shfl_down(ps, off);
    __shared__ float red[4];
    if ((tid & 63) == 0) red[tid >> 6] = ps;
    __syncthreads();
    if (tid == 0) biasf[h] = red[0] + red[1] + red[2] + red[3] + fc1_b[h];
}

// LSTM weights: concat [wih|whh] -> fp16 [2048 x 1024], rows reordered to h*4+gate.
__global__ __launch_bounds__(256) void prep_lstm(const float* __restrict__ wih,
                                                 const float* __restrict__ whh,
                                                 const float* __restrict__ bih,
                                                 const float* __restrict__ bhh,
                                                 _Float16* __restrict__ Wc,
                                                 float* __restrict__ bc) {
    int idx = blockIdx.x * 256 + threadIdx.x;  // 2,097,152
    int rp = idx >> 10, cc = idx & 1023;
    int h = rp >> 2, g = rp & 3;
    int rsrc = g * 512 + h;
    float v = (cc < 512) ? wih[(size_t)rsrc * 512 + cc] : whh[(size_t)rsrc * 512 + cc - 512];
    Wc[idx] = (_Float16)v;
    if (idx < 2048) {
        int h2 = idx >> 2, g2 = idx & 3;
        bc[idx] = bih[g2 * 512 + h2] + bhh[g2 * 512 + h2];
    }
}

__global__ __launch_bounds__(256) void prep_fc2t(const float* __restrict__ aw,
                                                 const float* __restrict__ bw,
                                                 const float* __restrict__ cw,
                                                 _Float16* __restrict__ aT,
                                                 _Float16* __restrict__ bT,
                                                 _Float16* __restrict__ cT) {
    int i = blockIdx.x * 256 + threadIdx.x;
    if (i < 131072) {
        int k = i >> 8, j = i & 255;
        aT[k * 256 + j] = (_Float16)aw[j * 512 + k];
    } else if (i < 131072 + 32768) {
        int i2 = i - 131072, k = i2 >> 7, j = i2 & 127;
        bT[k * 128 + j] = (_Float16)bw[j * 256 + k];
    } else if (i < 131072 + 32768 + 256) {
        int i3 = i - 131072 - 32768, k = i3 >> 1, o = i3 & 1;
        cT[k * 2 + o] = (_Float16)cw[o * 128 + k];
    }
}

__global__ __launch_bounds__(256) void bcast_G(const _Float16* __restrict__ d_h,
                                               _Float16* __restrict__ G) {
    const int b = blockIdx.x, tid = threadIdx.x;
    f16x4 v = *(const f16x4*)(d_h + tid * 4);
    *(f16x4*)(G + (size_t)b * 1024 + tid * 4) = v;
}

// ---------------------------------------------------------------- GEMM core
// acc layout: D row=(lane>>4)*4+r, col=lane&15 per 16x16 tile.
template <int BM, int BN, int BK, int WM, int WN>
DEVI void gemm_core(char* smem_raw, const _Float16* __restrict__ X, int ldx,
                    const _Float16* __restrict__ W, int ldw, int K,
                    int bm0, int bn0, f32x4* acc) {
    constexpr int LDT = BK + 8;
    _Float16* Xs = (_Float16*)smem_raw;
    _Float16* Ws = Xs + BM * LDT;
    const int tid = threadIdx.x, wave = tid >> 6, lane = tid & 63;
    constexpr int WROWS = BM / WM;
    const int wm = wave % WROWS, wn = wave / WROWS;
    constexpr int MT = WM / 16, NT = WN / 16;
    const int q = lane >> 4, m15 = lane & 15;
    constexpr int CPR = BK / 8;
    constexpr int XCH = BM * CPR, WCH = BN * CPR;
    for (int k0 = 0; k0 < K; k0 += BK) {
        #pragma unroll
        for (int c = tid; c < XCH; c += 256) {
            int row = c / CPR, col = (c % CPR) * 8;
            *(uint4*)&Xs[row * LDT + col] = *(const uint4*)&X[(size_t)(bm0 + row) * ldx + k0 + col];
        }
        #pragma unroll
        for (int c = tid; c < WCH; c += 256) {
            int row = c / CPR, col = (c % CPR) * 8;
            *(uint4*)&Ws[row * LDT + col] = *(const uint4*)&W[(size_t)(bn0 + row) * ldw + k0 + col];
        }
        __syncthreads();
        #pragma unroll
        for (int kk = 0; kk < BK / 32; ++kk) {
            f16x8 af[MT], bf[NT];
            #pragma unroll
            for (int i = 0; i < MT; ++i)
                af[i] = *(const f16x8*)&Xs[(wm * WM + i * 16 + m15) * LDT + kk * 32 + q * 8];
            #pragma unroll
            for (int j = 0; j < NT; ++j)
                bf[j] = *(const f16x8*)&Ws[(wn * WN + j * 16 + m15) * LDT + kk * 32 + q * 8];
            #pragma unroll
            for (int i = 0; i < MT; ++i)
                #pragma unroll
                for (int j = 0; j < NT; ++j)
                    acc[i * NT + j] = __builtin_amdgcn_mfma_f32_16x16x32_f16(af[i], bf[j], acc[i * NT + j], 0, 0, 0);
        }
        __syncthreads();
    }
}

template <int BM, int BN, int WM, int WN, int ACT>
DEVI void epi_plain(const f32x4* acc, const float* __restrict__ bias,
                    _Float16* __restrict__ out, int ldo, int bm0, int bn0) {
    const int tid = threadIdx.x, wave = tid >> 6, lane = tid & 63;
    constexpr int WROWS = BM / WM;
    const int wm = wave % WROWS, wn = wave / WROWS;
    constexpr int MT = WM / 16, NT = WN / 16;
    const int q = lane >> 4, m15 = lane & 15;
    #pragma unroll
    for (int i = 0; i < MT; ++i) {
        #pragma unroll
        for (int j = 0; j < NT; ++j) {
            int col = bn0 + wn * WN + j * 16 + m15;
            float bv = bias[col];
            #pragma unroll
            for (int r = 0; r < 4; ++r) {
                int rowg = bm0 + wm * WM + i * 16 + q * 4 + r;
                float v = acc[i * NT + j][r] + bv;
                if (ACT == 1) v = lrelu(v);
                out[(size_t)rowg * ldo + col] = (_Float16)v;
            }
        }
    }
}

template <int BM, int BN, int BK, int WM, int WN, int ACT>
__global__ __launch_bounds__(256) void gemm_k(const _Float16* __restrict__ X, int ldx,
                                              const _Float16* __restrict__ W, int ldw,
                                              const float* __restrict__ bias,
                                              _Float16* __restrict__ out, int ldo, int K) {
    __shared__ char smem[(BM + BN) * (BK + 8) * 2];
    constexpr int NACC = (WM / 16) * (WN / 16);
    f32x4 acc[NACC] = {};
    gemm_core<BM, BN, BK, WM, WN>(smem, X, ldx, W, ldw, K, blockIdx.y * BM, blockIdx.x * BN, acc);
    epi_plain<BM, BN, WM, WN, ACT>(acc, bias, out, ldo, blockIdx.y * BM, blockIdx.x * BN);
}

// ---------------------------------------------------------------- LSTM GEMM (fused gate ew)
// Weight rows are h*4+gate, so each 64-col block owns 16 h values x 4 gates.
template <bool HB>
__global__ __launch_bounds__(256) void gemm_lstm(const _Float16* __restrict__ X,
                                                 const _Float16* __restrict__ W,
                                                 const float* __restrict__ bias,
                                                 float* __restrict__ cvec,
                                                 _Float16* __restrict__ h0,
                                                 _Float16* __restrict__ h1) {
    __shared__ char smem[(64 + 64) * 72 * 2];
    const int bm0 = blockIdx.y * 64, bn0 = blockIdx.x * 64;
    f32x4 acc[4] = {};
    gemm_core<64, 64, 64, 32, 32>(smem, X, 1024, W, 1024, 1024, bm0, bn0, acc);
    float* accs = (float*)smem;  // [64][68]
    const int tid = threadIdx.x, wave = tid >> 6, lane = tid & 63;
    const int wm = wave & 1, wn = wave >> 1, q = lane >> 4, m15 = lane & 15;
    #pragma unroll
    for (int i = 0; i < 2; ++i) {
        #pragma unroll
        for (int j = 0; j < 2; ++j) {
            int cl = wn * 32 + j * 16 + m15;
            float bv = bias[bn0 + cl];
            #pragma unroll
            for (int r = 0; r < 4; ++r) {
                int rl = wm * 32 + i * 16 + q * 4 + r;
                accs[rl * 68 + cl] = acc[i * 2 + j][r] + bv;
            }
        }
    }
    __syncthreads();
    #pragma unroll
    for (int u = 0; u < 4; ++u) {
        int pair = tid + u * 256;       // 64 rows x 16 h
        int bl = pair >> 4, hl = pair & 15;
        float4 g4 = *(const float4*)&accs[bl * 68 + hl * 4];  // i,f,g,o
        int h = (bn0 >> 2) + hl, gb = bm0 + bl;
        float cold = cvec[gb * 512 + h];
        float cn = sigm(g4.y) * cold + sigm(g4.x) * tanh_f(g4.z);
        cvec[gb * 512 + h] = cn;
        _Float16 hn = (_Float16)(sigm(g4.w) * tanh_f(cn));
        h0[(size_t)gb * 1024 + h] = hn;
        if (HB) h1[(size_t)gb * 1024 + h] = hn;
    }
}

// ---------------------------------------------------------------- attention step
// One block per batch b. enc[b] (50 KB) staged to LDS once; G frags in regs.
__global__ __launch_bounds__(256) void attn_step(const _Float16* __restrict__ G,
                                                 const _Float16* __restrict__ encH,
                                                 const float* __restrict__ z,
                                                 _Float16* __restrict__ eb, int t) {
    __shared__ _Float16 encs[SEQ * ENC];   // 51200 B
    __shared__ _Float16 gs[1024];
    __shared__ float sc[4][128];
    __shared__ float wsm[4][128];
    const int b = blockIdx.x, tid = threadIdx.x;
    if (tid < 128) *(uint4*)&gs[tid * 8] = *(const uint4*)&G[(size_t)b * 1024 + tid * 8];
    {   // stage enc: 3200 x 16B chunks, 12 outstanding loads per thread
        const uint4* src = (const uint4*)(encH + (size_t)b * SEQ * ENC);
        uint4* dst = (uint4*)encs;
        #pragma unroll
        for (int i = 0; i < 12; ++i) dst[tid + i * 256] = src[tid + i * 256];
        if (tid < 128) dst[tid + 3072] = src[tid + 3072];
    }
    __syncthreads();
    {   // phase 1: 400 score dots, 16-lane groups; G frags hoisted (n fixed per group)
        const int grp = tid >> 4, l16 = tid & 15, n = grp & 3, wv4 = grp >> 2;
        f16x8 g0 = *(const f16x8*)&gs[n * 256 + l16 * 8];
        f16x8 g1 = *(const f16x8*)&gs[n * 256 + 128 + l16 * 8];
        #pragma unroll 5
        for (int it = 0; it < 25; ++it) {
            int s = it * 4 + wv4;
            f16x8 e0 = *(const f16x8*)&encs[s * ENC + l16 * 8];
            f16x8 e1 = *(const f16x8*)&encs[s * ENC + 128 + l16 * 8];
            float p = 0.f;
            #pragma unroll
            for (int j = 0; j < 8; ++j)
                p += (float)e0[j] * (float)g0[j] + (float)e1[j] * (float)g1[j];
            p += __shfl_xor(p, 1); p += __shfl_xor(p, 2);
            p += __shfl_xor(p, 4); p += __shfl_xor(p, 8);
            if (l16 == 0) sc[n][s] = p;
        }
    }
    __syncthreads();
    const int wv = tid >> 6, ln = tid & 63;
    {   // phase 2: softmax per head (one wave per head)
        float v0 = sc[wv][ln];
        float v1 = (ln < SEQ - 64) ? sc[wv][64 + ln] : -1e30f;
        float m = fmaxf(v0, v1);
        #pragma unroll
        for (int off = 32; off; off >>= 1) m = fmaxf(m, __shfl_xor(m, off));
        float e0 = __expf(v0 - m);
        float e1 = (ln < SEQ - 64) ? __expf(v1 - m) : 0.f;
        float ss = e0 + e1;
        #pragma unroll
        for (int off = 32; off; off >>= 1) ss += __shfl_xor(ss, off);
        float inv = 1.f / ss;
        wsm[wv][ln] = e0 * inv;
        if (ln < SEQ - 64) wsm[wv][64 + ln] = e1 * inv;
    }
    __syncthreads();
    {   // phase 3: e-bar[n,:] = sum_s w[n,s]*enc[s,:]; one wave per head
        float a0 = 0.f, a1 = 0.f, a2 = 0.f, a3 = 0.f;
        #pragma unroll 4
        for (int s = 0; s < SEQ; ++s) {
            f16x4 e4 = *(const f16x4*)&encs[s * ENC + ln * 4];
            float w = wsm[wv][s];
            a0 += w * (float)e4.x; a1 += w * (float)e4.y;
            a2 += w * (float)e4.z; a3 += w * (float)e4.w;
        }
        f16x4 r;
        r.x = (_Float16)a0; r.y = (_Float16)a1; r.z = (_Float16)a2; r.w = (_Float16)a3;
        *(f16x4*)(eb + (size_t)b * 1088 + wv * ENC + ln * 4) = r;
    }
    if (tid < LAT)
        eb[(size_t)b * 1088 + 1024 + tid] = (_Float16)z[((size_t)b * TT + t) * LAT + tid];
}

// ---------------------------------------------------------------- fc2 chain + next-step q GEMM
__device__ void fc2_body(_Float16* smem, const _Float16* __restrict__ xh2,
                         const _Float16* __restrict__ aT, const float* __restrict__ ab,
                         const _Float16* __restrict__ bT, const float* __restrict__ bb,
                         const _Float16* __restrict__ cT, const float* __restrict__ cb,
                         float* __restrict__ out, int b0, int t) {
    _Float16* h2s = smem;          // 4*512
    _Float16* y1s = smem + 2048;   // 4*256
    _Float16* y2s = smem + 3072;   // 4*128
    const int tid = threadIdx.x;
    {
        int r = tid >> 6, k = (tid & 63) * 8;
        *(uint4*)&h2s[r * 512 + k] = *(const uint4*)&xh2[(size_t)(b0 + r) * 1024 + 512 + k];
    }
    __syncthreads();
    {
        float a0 = 0.f, a1 = 0.f, a2 = 0.f, a3 = 0.f;
        for (int k = 0; k < 512; ++k) {
            float w = (float)aT[k * 256 + tid];
            a0 += w * (float)h2s[k];        a1 += w * (float)h2s[512 + k];
            a2 += w * (float)h2s[1024 + k]; a3 += w * (float)h2s[1536 + k];
        }
        float bj = ab[tid];
        y1s[tid]       = (_Float16)lrelu(a0 + bj);
        y1s[256 + tid] = (_Float16)lrelu(a1 + bj);
        y1s[512 + tid] = (_Float16)lrelu(a2 + bj);
        y1s[768 + tid] = (_Float16)lrelu(a3 + bj);
    }
    __syncthreads();
    if (tid < 128) {
        float a0 = 0.f, a1 = 0.f, a2 = 0.f, a3 = 0.f;
        for (int k = 0; k < 256; ++k) {
            float w = (float)bT[k * 128 + tid];
            a0 += w * (float)y1s[k];       a1 += w * (float)y1s[256 + k];
            a2 += w * (float)y1s[512 + k]; a3 += w * (float)y1s[768 + k];
        }
        float bj = bb[tid];
        y2s[tid]       = (_Float16)lrelu(a0 + bj);
        y2s[128 + tid] = (_Float16)lrelu(a1 + bj);
        y2s[256 + tid] = (_Float16)lrelu(a2 + bj);
        y2s[384 + tid] = (_Float16)lrelu(a3 + bj);
    }
    __syncthreads();
    if (tid < 8) {
        int r = tid >> 1, o = tid & 1;
        float acc = cb[o];
        for (int k = 0; k < 128; ++k) acc += (float)cT[k * 2 + o] * (float)y2s[r * 128 + k];
        out[((size_t)(b0 + r) * TT + t) * 2 + o] = tanhf(acc);
    }
}

// blocks 0..255: G(t+1) = h2 @ C^T + d ; blocks 256..511: fc2 output for step t.
__global__ __launch_bounds__(256) void out_and_q(const _Float16* __restrict__ xh2,
                                                 const _Float16* __restrict__ C_h,
                                                 const float* __restrict__ d_f,
                                                 _Float16* __restrict__ G,
                                                 const _Float16* __restrict__ aT, const float* __restrict__ ab,
                                                 const _Float16* __restrict__ bT, const float* __restrict__ bb,
                                                 const _Float16* __restrict__ cT, const float* __restrict__ cb,
                                                 float* __restrict__ out, int t, int do_gemm) {
    __shared__ char smem[(64 + 64) * 72 * 2];
    if (blockIdx.x < 256) {
        if (!do_gemm) return;
        const int bm0 = (blockIdx.x >> 4) * 64, bn0 = (blockIdx.x & 15) * 64;
        f32x4 acc[4] = {};
        gemm_core<64, 64, 64, 32, 32>(smem, xh2 + 512, 1024, C_h, 512, 512, bm0, bn0, acc);
        epi_plain<64, 64, 32, 32, 0>(acc, d_f, G, 1024, bm0, bn0);
    } else {
        fc2_body((_Float16*)smem, xh2, aT, ab, bT, bb, cT, cb, out, (blockIdx.x - 256) * 4, t);
    }
}

// ---------------------------------------------------------------- launch
extern "C" void kernel_launch(void* const* d_in, const int* in_sizes, int n_in,
                              void* d_out, int out_size, void* d_ws, size_t ws_size,
                              hipStream_t stream) {
    const float* encoded = (const float*)d_in[0];
    const float* z       = (const float*)d_in[1];
    const float* q_w     = (const float*)d_in[2];
    const float* k_w     = (const float*)d_in[3];
    const float* v_w     = (const float*)d_in[4];
    const float* q_b     = (const float*)d_in[5];
    // d_in[6] (k_b): softmax-invariant — dropped exactly.
    const float* v_b     = (const float*)d_in[7];
    const float* out_w   = (const float*)d_in[8];
    const float* out_b   = (const float*)d_in[9];
    const float* fc1_w   = (const float*)d_in[10];
    const float* fc1_b   = (const float*)d_in[11];
    const float* l1_wih  = (const float*)d_in[12];
    const float* l1_whh  = (const float*)d_in[13];
    const float* l1_bih  = (const float*)d_in[14];
    const float* l1_bhh  = (const float*)d_in[15];
    const float* l2_wih  = (const float*)d_in[16];
    const float* l2_whh  = (const float*)d_in[17];
    const float* l2_bih  = (const float*)d_in[18];
    const float* l2_bhh  = (const float*)d_in[19];
    const float* fc2a_w  = (const float*)d_in[20];
    const float* fc2a_b  = (const float*)d_in[21];
    const float* fc2b_w  = (const float*)d_in[22];
    const float* fc2b_b  = (const float*)d_in[23];
    const float* fc2c_w  = (const float*)d_in[24];
    const float* fc2c_b  = (const float*)d_in[25];
    float* out = (float*)d_out;

    char* p = (char*)d_ws;
    auto take = [&](size_t bytes) { char* r = p; p += (bytes + 255) & ~(size_t)255; return r; };
    _Float16* encH  = (_Float16*)take(52428800);   // [1024,100,256] fp16
    _Float16* C_h   = (_Float16*)take(1048576);    // [1024,512]
    _Float16* Wfc1  = (_Float16*)take(1114112);    // [512,1088]
    _Float16* L1W   = (_Float16*)take(4194304);    // [2048,1024] rows h*4+g
    _Float16* L2W   = (_Float16*)take(4194304);
    _Float16* fc2aT = (_Float16*)take(262144);
    _Float16* fc2bT = (_Float16*)take(65536);
    _Float16* fc2cT = (_Float16*)take(512);
    _Float16* eb    = (_Float16*)take(2228224);    // [1024,1088]
    char* zreg = p;                                // ---- zero region (10 MB) ----
    _Float16* xh1 = (_Float16*)take(2097152);      // [1024,1024] = [fc1out | h1]
    _Float16* xh2 = (_Float16*)take(2097152);      // [1024,1024] = [h1 | h2]
    _Float16* G   = (_Float16*)take(2097152);      // [1024,1024]
    float* c1     = (float*)take(2097152);
    float* c2     = (float*)take(2097152);         // ---- end zero region ----
    float* A      = (float*)take(1048576);
    float* d_f    = (float*)take(4096);
    _Float16* d_h = (_Float16*)take(2048);
    float* biasf  = (float*)take(2048);
    float* L1b    = (float*)take(8192);
    float* L2b    = (float*)take(8192);
    (void)in_sizes; (void)n_in; (void)out_size; (void)ws_size;

    zero_ws<<<2560, 256, 0, stream>>>((uint4*)zreg);
    conv_enc<<<25600, 256, 0, stream>>>((const float4*)encoded, (f16x4*)encH);
    prep_qk<<<1024, 256, 0, stream>>>(k_w, q_w, q_b, C_h, d_f, d_h);
    prep_A<<<512, 256, 0, stream>>>(fc1_w, out_w, A);
    prep_wfc1<<<512, 256, 0, stream>>>(A, v_w, v_b, fc1_w, out_b, fc1_b, Wfc1, biasf);
    prep_lstm<<<8192, 256, 0, stream>>>(l1_wih, l1_whh, l1_bih, l1_bhh, L1W, L1b);
    prep_lstm<<<8192, 256, 0, stream>>>(l2_wih, l2_whh, l2_bih, l2_bhh, L2W, L2b);
    prep_fc2t<<<641, 256, 0, stream>>>(fc2a_w, fc2b_w, fc2c_w, fc2aT, fc2bT, fc2cT);
    bcast_G<<<1024, 256, 0, stream>>>(d_h, G);

    for (int t = 0; t < TT; ++t) {
        attn_step<<<1024, 256, 0, stream>>>(G, encH, z, eb, t);
        // fc1: [1024,1088] @ [512,1088]^T, lrelu -> xh1[:, :512]
        gemm_k<64, 32, 64, 16, 32, 1><<<dim3(16, 16), 256, 0, stream>>>(
            eb, 1088, Wfc1, 1088, biasf, xh1, 1024, 1088);
        // LSTM1: gates GEMM + fused ew -> h1 (xh1[:,512:], xh2[:,:512]), c1
        gemm_lstm<true><<<dim3(32, 16), 256, 0, stream>>>(xh1, L1W, L1b, c1, xh1 + 512, xh2);
        // LSTM2 -> h2 (xh2[:,512:]), c2
        gemm_lstm<false><<<dim3(32, 16), 256, 0, stream>>>(xh2, L2W, L2b, c2, xh2 + 512, nullptr);
        // fc2 output for step t + q-projection GEMM for step t+1
        out_and_q<<<512, 256, 0, stream>>>(xh2, C_h, d_f, G,
                                           fc2aT, fc2a_b, fc2bT, fc2b_b, fc2cT, fc2c_b,
                                           out, t, (t < TT - 1) ? 1 : 0);
    }
}

// Round 3
// 4051.950 us; speedup vs baseline: 1.4729x; 1.1622x over previous
//
#include <hip/hip_runtime.h>

// Generator_78683800862785: attention+LSTM decoder, BS=1024, T=30.
// fp16 MFMA GEMMs w/ fp32 accum; K/V folded into C = scale*K_w^T Q_w;
// att->out->fc1 folded into Wfc1; LSTM gate-ew fused into GEMM epilogue
// (weights row-reordered to h*4+gate); fc2 chain as MFMA; register
// double-buffered K-loops. 5 launches per step.

#define DEVI __device__ __forceinline__

typedef _Float16 f16x8 __attribute__((ext_vector_type(8)));
typedef _Float16 f16x4 __attribute__((ext_vector_type(4)));
typedef float    f32x4 __attribute__((ext_vector_type(4)));

#define BSZ 1024
#define SEQ 100
#define ENC 256
#define HID 512
#define LAT 64
#define TT  30

// ---------------------------------------------------------------- utilities
DEVI float lrelu(float v) { return v >= 0.f ? v : 0.2f * v; }
DEVI float sigm(float x)  { return 1.f / (1.f + __expf(-x)); }
DEVI float tanh_f(float x){ return 1.f - 2.f / (1.f + __expf(2.f * x)); }

// ---------------------------------------------------------------- setup kernels
__global__ __launch_bounds__(256) void zero_ws(uint4* __restrict__ p) {
    uint4 z; z.x = z.y = z.z = z.w = 0u;
    p[(size_t)blockIdx.x * 256 + threadIdx.x] = z;
}

__global__ __launch_bounds__(256) void conv_enc(const float4* __restrict__ src,
                                                f16x4* __restrict__ dst) {
    size_t i = (size_t)blockIdx.x * 256 + threadIdx.x;
    float4 v = src[i];
    f16x4 h;
    h.x = (_Float16)v.x; h.y = (_Float16)v.y; h.z = (_Float16)v.z; h.w = (_Float16)v.w;
    dst[i] = h;
}

// C[ne,h] = scale * sum_d k_w[n*128+d, e] * q_w[n*128+d, h]   (fp16 out)
// d[ne]   = scale * sum_d k_w[n*128+d, e] * q_b[n*128+d]
__global__ __launch_bounds__(256) void prep_qk(const float* __restrict__ k_w,
                                               const float* __restrict__ q_w,
                                               const float* __restrict__ q_b,
                                               _Float16* __restrict__ C_h,
                                               float* __restrict__ d_f,
                                               _Float16* __restrict__ d_h) {
    const int ne = blockIdx.x, n = ne >> 8, e = ne & 255, tid = threadIdx.x;
    const float scale = 0.08838834764831845f;  // 1/sqrt(128)
    float a0 = 0.f, a1 = 0.f;
    for (int dd = 0; dd < 128; ++dd) {
        float kv = k_w[(n * 128 + dd) * 256 + e];
        a0 += kv * q_w[(n * 128 + dd) * 512 + tid];
        a1 += kv * q_w[(n * 128 + dd) * 512 + 256 + tid];
    }
    C_h[(size_t)ne * 512 + tid]       = (_Float16)(scale * a0);
    C_h[(size_t)ne * 512 + 256 + tid] = (_Float16)(scale * a1);
    float pq = (tid < 128) ? k_w[(n * 128 + tid) * 256 + e] * q_b[n * 128 + tid] : 0.f;
    #pragma unroll
    for (int off = 32; off; off >>= 1) pq += __shfl_down(pq, off);
    __shared__ float red[4];
    if ((tid & 63) == 0) red[tid >> 6] = pq;
    __syncthreads();
    if (tid == 0) {
        float s = scale * (red[0] + red[1] + red[2] + red[3]);
        d_f[ne] = s; d_h[ne] = (_Float16)s;
    }
}

// A[h,k] = sum_m fc1_w[h, m] * out_w[m, k]
__global__ __launch_bounds__(256) void prep_A(const float* __restrict__ fc1_w,
                                              const float* __restrict__ out_w,
                                              float* __restrict__ A) {
    const int h = blockIdx.x, tid = threadIdx.x;
    float a0 = 0.f, a1 = 0.f;
    for (int m = 0; m < 512; ++m) {
        float fv = fc1_w[h * 576 + m];
        a0 += fv * out_w[m * 512 + tid];
        a1 += fv * out_w[m * 512 + 256 + tid];
    }
    A[(size_t)h * 512 + tid]       = a0;
    A[(size_t)h * 512 + 256 + tid] = a1;
}

// Wfc1[h, n*256+e] = sum_d A[h, n*128+d]*v_w[n*128+d, e]; cols 1024..1087 = fc1_w[h,512+l]
__global__ __launch_bounds__(256) void prep_wfc1(const float* __restrict__ A,
                                                 const float* __restrict__ v_w,
                                                 const float* __restrict__ v_b,
                                                 const float* __restrict__ fc1_w,
                                                 const float* __restrict__ out_b,
                                                 const float* __restrict__ fc1_b,
                                                 _Float16* __restrict__ Wfc1,
                                                 float* __restrict__ biasf) {
    const int h = blockIdx.x, tid = threadIdx.x;
    #pragma unroll
    for (int g = 0; g < 4; ++g) {
        float acc = 0.f;
        for (int dd = 0; dd < 128; ++dd)
            acc += A[h * 512 + g * 128 + dd] * v_w[(g * 128 + dd) * 256 + tid];
        Wfc1[(size_t)h * 1088 + g * 256 + tid] = (_Float16)acc;
    }
    if (tid < 64)
        Wfc1[(size_t)h * 1088 + 1024 + tid] = (_Float16)fc1_w[h * 576 + 512 + tid];
    float ps = A[h * 512 + tid] * v_b[tid] + A[h * 512 + 256 + tid] * v_b[256 + tid]
             + fc1_w[h * 576 + tid] * out_b[tid] + fc1_w[h * 576 + 256 + tid] * out_b[256 + tid];
    #pragma unroll
    for (int off = 32; off; off >>= 1) ps += __shfl_down(ps, off);
    __shared__ float red[4];
    if ((tid & 63) == 0) red[tid >> 6] = ps;
    __syncthreads();
    if (tid == 0) biasf[h] = red[0] + red[1] + red[2] + red[3] + fc1_b[h];
}

// LSTM weights: concat [wih|whh] -> fp16 [2048 x 1024], rows reordered to h*4+gate.
__global__ __launch_bounds__(256) void prep_lstm(const float* __restrict__ wih,
                                                 const float* __restrict__ whh,
                                                 const float* __restrict__ bih,
                                                 const float* __restrict__ bhh,
                                                 _Float16* __restrict__ Wc,
                                                 float* __restrict__ bc) {
    int idx = blockIdx.x * 256 + threadIdx.x;  // 2,097,152
    int rp = idx >> 10, cc = idx & 1023;
    int h = rp >> 2, g = rp & 3;
    int rsrc = g * 512 + h;
    float v = (cc < 512) ? wih[(size_t)rsrc * 512 + cc] : whh[(size_t)rsrc * 512 + cc - 512];
    Wc[idx] = (_Float16)v;
    if (idx < 2048) {
        int h2 = idx >> 2, g2 = idx & 3;
        bc[idx] = bih[g2 * 512 + h2] + bhh[g2 * 512 + h2];
    }
}

// fc2 weights -> straight fp16 casts (no transpose; GEMMs run X @ W^T).
__global__ __launch_bounds__(256) void prep_fc2c(const float* __restrict__ aw,
                                                 const float* __restrict__ bw,
                                                 const float* __restrict__ cw,
                                                 _Float16* __restrict__ a16,
                                                 _Float16* __restrict__ b16,
                                                 _Float16* __restrict__ c16) {
    int i = blockIdx.x * 256 + threadIdx.x;
    if (i < 131072) a16[i] = (_Float16)aw[i];
    else if (i < 163840) b16[i - 131072] = (_Float16)bw[i - 131072];
    else if (i < 164096) c16[i - 163840] = (_Float16)cw[i - 163840];
}

__global__ __launch_bounds__(256) void bcast_G(const _Float16* __restrict__ d_h,
                                               _Float16* __restrict__ G) {
    const int b = blockIdx.x, tid = threadIdx.x;
    f16x4 v = *(const f16x4*)(d_h + tid * 4);
    *(f16x4*)(G + (size_t)b * 1024 + tid * 4) = v;
}

// ---------------------------------------------------------------- GEMM core (reg double-buffered)
// Computes out = X @ W^T on a BMxBN tile. W row-major [N,K].
// acc layout per 16x16 tile: row=(lane>>4)*4+r, col=lane&15.
template <int NTHR, int BM, int BN, int BK, int WM, int WN>
DEVI void gemm_core_db(char* smem_raw, const _Float16* __restrict__ X, int ldx,
                       const _Float16* __restrict__ W, int ldw, int K,
                       int bm0, int bn0, f32x4* acc) {
    constexpr int LDT = BK + 8;
    _Float16* Xs = (_Float16*)smem_raw;
    _Float16* Ws = Xs + BM * LDT;
    const int tid = threadIdx.x, wave = tid >> 6, lane = tid & 63;
    constexpr int WROWS = BM / WM;
    const int wm = wave % WROWS, wn = wave / WROWS;
    constexpr int MT = WM / 16, NT = WN / 16;
    const int q = lane >> 4, m15 = lane & 15;
    constexpr int CPR = BK / 8;
    constexpr int XPT = BM * CPR / NTHR;
    constexpr int WPT = BN * CPR / NTHR;
    static_assert(BM * CPR % NTHR == 0 && BN * CPR % NTHR == 0, "chunk split");
    uint4 xr[XPT], wr[WPT];
    auto ldregs = [&](int k0) {
        #pragma unroll
        for (int c = 0; c < XPT; ++c) {
            int cc = tid + c * NTHR, row = cc / CPR, col = (cc % CPR) * 8;
            xr[c] = *(const uint4*)&X[(size_t)(bm0 + row) * ldx + k0 + col];
        }
        #pragma unroll
        for (int c = 0; c < WPT; ++c) {
            int cc = tid + c * NTHR, row = cc / CPR, col = (cc % CPR) * 8;
            wr[c] = *(const uint4*)&W[(size_t)(bn0 + row) * ldw + k0 + col];
        }
    };
    ldregs(0);
    for (int k0 = 0; k0 < K; k0 += BK) {
        #pragma unroll
        for (int c = 0; c < XPT; ++c) {
            int cc = tid + c * NTHR, row = cc / CPR, col = (cc % CPR) * 8;
            *(uint4*)&Xs[row * LDT + col] = xr[c];
        }
        #pragma unroll
        for (int c = 0; c < WPT; ++c) {
            int cc = tid + c * NTHR, row = cc / CPR, col = (cc % CPR) * 8;
            *(uint4*)&Ws[row * LDT + col] = wr[c];
        }
        __syncthreads();
        if (k0 + BK < K) ldregs(k0 + BK);   // overlap next-tile loads with MFMA phase
        #pragma unroll
        for (int kk = 0; kk < BK / 32; ++kk) {
            f16x8 af[MT], bf[NT];
            #pragma unroll
            for (int i = 0; i < MT; ++i)
                af[i] = *(const f16x8*)&Xs[(wm * WM + i * 16 + m15) * LDT + kk * 32 + q * 8];
            #pragma unroll
            for (int j = 0; j < NT; ++j)
                bf[j] = *(const f16x8*)&Ws[(wn * WN + j * 16 + m15) * LDT + kk * 32 + q * 8];
            #pragma unroll
            for (int i = 0; i < MT; ++i)
                #pragma unroll
                for (int j = 0; j < NT; ++j)
                    acc[i * NT + j] = __builtin_amdgcn_mfma_f32_16x16x32_f16(af[i], bf[j], acc[i * NT + j], 0, 0, 0);
        }
        __syncthreads();
    }
}

template <int BM, int BN, int WM, int WN, int ACT>
DEVI void epi_plain(const f32x4* acc, const float* __restrict__ bias,
                    _Float16* __restrict__ out, int ldo, int bm0, int bn0) {
    const int tid = threadIdx.x, wave = tid >> 6, lane = tid & 63;
    constexpr int WROWS = BM / WM;
    const int wm = wave % WROWS, wn = wave / WROWS;
    constexpr int MT = WM / 16, NT = WN / 16;
    const int q = lane >> 4, m15 = lane & 15;
    #pragma unroll
    for (int i = 0; i < MT; ++i) {
        #pragma unroll
        for (int j = 0; j < NT; ++j) {
            int col = bn0 + wn * WN + j * 16 + m15;
            float bv = bias[col];
            #pragma unroll
            for (int r = 0; r < 4; ++r) {
                int rowg = bm0 + wm * WM + i * 16 + q * 4 + r;
                float v = acc[i * NT + j][r] + bv;
                if (ACT == 1) v = lrelu(v);
                out[(size_t)rowg * ldo + col] = (_Float16)v;
            }
        }
    }
}

template <int NTHR, int BM, int BN, int BK, int WM, int WN, int ACT>
__global__ __launch_bounds__(NTHR) void gemm_k(const _Float16* __restrict__ X, int ldx,
                                               const _Float16* __restrict__ W, int ldw,
                                               const float* __restrict__ bias,
                                               _Float16* __restrict__ out, int ldo, int K) {
    __shared__ char smem[(BM + BN) * (BK + 8) * 2];
    constexpr int NACC = (WM / 16) * (WN / 16);
    f32x4 acc[NACC] = {};
    gemm_core_db<NTHR, BM, BN, BK, WM, WN>(smem, X, ldx, W, ldw, K,
                                           blockIdx.y * BM, blockIdx.x * BN, acc);
    epi_plain<BM, BN, WM, WN, ACT>(acc, bias, out, ldo, blockIdx.y * BM, blockIdx.x * BN);
}

// ---------------------------------------------------------------- LSTM GEMM (fused gate ew)
// 512 threads, 64x128 tile, grid 16x16 = 256 blocks (1/CU, 8 waves).
// Weight rows are h*4+gate: each 128-col block owns 32 h values x 4 gates.
template <bool HB>
__global__ __launch_bounds__(512) void gemm_lstm(const _Float16* __restrict__ X,
                                                 const _Float16* __restrict__ W,
                                                 const float* __restrict__ bias,
                                                 float* __restrict__ cvec,
                                                 _Float16* __restrict__ h0,
                                                 _Float16* __restrict__ h1) {
    __shared__ char smem[64 * 132 * 4];   // 33792 B: max(gemm 27648, epi 33792)
    const int bm0 = blockIdx.y * 64, bn0 = blockIdx.x * 128;
    f32x4 acc[4] = {};
    gemm_core_db<512, 64, 128, 64, 32, 32>(smem, X, 1024, W, 1024, 1024, bm0, bn0, acc);
    float* accs = (float*)smem;  // [64][132]
    const int tid = threadIdx.x, wave = tid >> 6, lane = tid & 63;
    const int wm = wave & 1, wn = wave >> 1, q = lane >> 4, m15 = lane & 15;
    #pragma unroll
    for (int i = 0; i < 2; ++i) {
        #pragma unroll
        for (int j = 0; j < 2; ++j) {
            int cl = wn * 32 + j * 16 + m15;
            float bv = bias[bn0 + cl];
            #pragma unroll
            for (int r = 0; r < 4; ++r) {
                int rl = wm * 32 + i * 16 + q * 4 + r;
                accs[rl * 132 + cl] = acc[i * 2 + j][r] + bv;
            }
        }
    }
    __syncthreads();
    #pragma unroll
    for (int u = 0; u < 4; ++u) {
        int pair = tid + u * 512;        // 64 rows x 32 h
        int bl = pair >> 5, hl = pair & 31;
        float4 g4 = *(const float4*)&accs[bl * 132 + hl * 4];  // i,f,g,o
        int h = (bn0 >> 2) + hl, gb = bm0 + bl;
        float cold = cvec[gb * 512 + h];
        float cn = sigm(g4.y) * cold + sigm(g4.x) * tanh_f(g4.z);
        cvec[gb * 512 + h] = cn;
        _Float16 hn = (_Float16)(sigm(g4.w) * tanh_f(cn));
        h0[(size_t)gb * 1024 + h] = hn;
        if (HB) h1[(size_t)gb * 1024 + h] = hn;
    }
}

// ---------------------------------------------------------------- attention step
__global__ __launch_bounds__(256) void attn_step(const _Float16* __restrict__ G,
                                                 const _Float16* __restrict__ encH,
                                                 const float* __restrict__ z,
                                                 _Float16* __restrict__ eb, int t) {
    __shared__ _Float16 encs[SEQ * ENC];   // 51200 B
    __shared__ _Float16 gs[1024];
    __shared__ float sc[4][128];
    __shared__ float wsm[4][128];
    const int b = blockIdx.x, tid = threadIdx.x;
    if (tid < 128) *(uint4*)&gs[tid * 8] = *(const uint4*)&G[(size_t)b * 1024 + tid * 8];
    {
        const uint4* src = (const uint4*)(encH + (size_t)b * SEQ * ENC);
        uint4* dst = (uint4*)encs;
        #pragma unroll
        for (int i = 0; i < 12; ++i) dst[tid + i * 256] = src[tid + i * 256];
        if (tid < 128) dst[tid + 3072] = src[tid + 3072];
    }
    __syncthreads();
    {   // scores: 16-lane groups, G frags hoisted
        const int grp = tid >> 4, l16 = tid & 15, n = grp & 3, wv4 = grp >> 2;
        f16x8 g0 = *(const f16x8*)&gs[n * 256 + l16 * 8];
        f16x8 g1 = *(const f16x8*)&gs[n * 256 + 128 + l16 * 8];
        #pragma unroll 5
        for (int it = 0; it < 25; ++it) {
            int s = it * 4 + wv4;
            f16x8 e0 = *(const f16x8*)&encs[s * ENC + l16 * 8];
            f16x8 e1 = *(const f16x8*)&encs[s * ENC + 128 + l16 * 8];
            float p = 0.f;
            #pragma unroll
            for (int j = 0; j < 8; ++j)
                p += (float)e0[j] * (float)g0[j] + (float)e1[j] * (float)g1[j];
            p += __shfl_xor(p, 1); p += __shfl_xor(p, 2);
            p += __shfl_xor(p, 4); p += __shfl_xor(p, 8);
            if (l16 == 0) sc[n][s] = p;
        }
    }
    __syncthreads();
    const int wv = tid >> 6, ln = tid & 63;
    {   // softmax per head
        float v0 = sc[wv][ln];
        float v1 = (ln < SEQ - 64) ? sc[wv][64 + ln] : -1e30f;
        float m = fmaxf(v0, v1);
        #pragma unroll
        for (int off = 32; off; off >>= 1) m = fmaxf(m, __shfl_xor(m, off));
        float e0 = __expf(v0 - m);
        float e1 = (ln < SEQ - 64) ? __expf(v1 - m) : 0.f;
        float ss = e0 + e1;
        #pragma unroll
        for (int off = 32; off; off >>= 1) ss += __shfl_xor(ss, off);
        float inv = 1.f / ss;
        wsm[wv][ln] = e0 * inv;
        if (ln < SEQ - 64) wsm[wv][64 + ln] = e1 * inv;
    }
    __syncthreads();
    {   // weighted sum
        float a0 = 0.f, a1 = 0.f, a2 = 0.f, a3 = 0.f;
        #pragma unroll 4
        for (int s = 0; s < SEQ; ++s) {
            f16x4 e4 = *(const f16x4*)&encs[s * ENC + ln * 4];
            float w = wsm[wv][s];
            a0 += w * (float)e4.x; a1 += w * (float)e4.y;
            a2 += w * (float)e4.z; a3 += w * (float)e4.w;
        }
        f16x4 r;
        r.x = (_Float16)a0; r.y = (_Float16)a1; r.z = (_Float16)a2; r.w = (_Float16)a3;
        *(f16x4*)(eb + (size_t)b * 1088 + wv * ENC + ln * 4) = r;
    }
    if (tid < LAT)
        eb[(size_t)b * 1088 + 1024 + tid] = (_Float16)z[((size_t)b * TT + t) * LAT + tid];
}

// ---------------------------------------------------------------- fc2 chain (MFMA, 16 batches/block)
DEVI void fc2_mfma(char* smem_raw, const _Float16* __restrict__ xh2,
                   const _Float16* __restrict__ Wa, const float* __restrict__ ab,
                   const _Float16* __restrict__ Wb, const float* __restrict__ bb,
                   const _Float16* __restrict__ Wc, const float* __restrict__ cb,
                   float* __restrict__ out, int b0, int t) {
    _Float16* h2s = (_Float16*)smem_raw;   // [16][520]
    _Float16* y1s = h2s + 16 * 520;        // [16][264]
    _Float16* y2s = y1s + 16 * 264;        // [16][136]
    const int tid = threadIdx.x, wave = tid >> 6, lane = tid & 63;
    const int q = lane >> 4, m15 = lane & 15;
    #pragma unroll
    for (int c = 0; c < 4; ++c) {
        int cc = tid + c * 256, row = cc >> 6, col = (cc & 63) * 8;
        *(uint4*)&h2s[row * 520 + col] = *(const uint4*)&xh2[(size_t)(b0 + row) * 1024 + 512 + col];
    }
    __syncthreads();
    {   // y1[16,256] = lrelu(h2 @ Wa^T + ab); wave handles 64 cols
        f32x4 acc[4] = {};
        #pragma unroll 4
        for (int kk = 0; kk < 16; ++kk) {
            f16x8 af = *(const f16x8*)&h2s[m15 * 520 + kk * 32 + q * 8];
            #pragma unroll
            for (int j = 0; j < 4; ++j) {
                int n = wave * 64 + j * 16 + m15;
                f16x8 bf = *(const f16x8*)&Wa[(size_t)n * 512 + kk * 32 + q * 8];
                acc[j] = __builtin_amdgcn_mfma_f32_16x16x32_f16(af, bf, acc[j], 0, 0, 0);
            }
        }
        #pragma unroll
        for (int j = 0; j < 4; ++j) {
            int col = wave * 64 + j * 16 + m15;
            float bv = ab[col];
            #pragma unroll
            for (int r = 0; r < 4; ++r)
                y1s[(q * 4 + r) * 264 + col] = (_Float16)lrelu(acc[j][r] + bv);
        }
    }
    __syncthreads();
    {   // y2[16,128] = lrelu(y1 @ Wb^T + bb); wave handles 32 cols
        f32x4 acc[2] = {};
        #pragma unroll
        for (int kk = 0; kk < 8; ++kk) {
            f16x8 af = *(const f16x8*)&y1s[m15 * 264 + kk * 32 + q * 8];
            #pragma unroll
            for (int j = 0; j < 2; ++j) {
                int n = wave * 32 + j * 16 + m15;
                f16x8 bf = *(const f16x8*)&Wb[(size_t)n * 256 + kk * 32 + q * 8];
                acc[j] = __builtin_amdgcn_mfma_f32_16x16x32_f16(af, bf, acc[j], 0, 0, 0);
            }
        }
        #pragma unroll
        for (int j = 0; j < 2; ++j) {
            int col = wave * 32 + j * 16 + m15;
            float bv = bb[col];
            #pragma unroll
            for (int r = 0; r < 4; ++r)
                y2s[(q * 4 + r) * 136 + col] = (_Float16)lrelu(acc[j][r] + bv);
        }
    }
    __syncthreads();
    if (tid < 32) {   // y3: 16 batches x 2 outs, tanh
        int r = tid >> 1, o = tid & 1;
        float acc = cb[o];
        #pragma unroll 8
        for (int k = 0; k < 128; ++k)
            acc += (float)Wc[o * 128 + k] * (float)y2s[r * 136 + k];
        out[((size_t)(b0 + r) * TT + t) * 2 + o] = tanhf(acc);
    }
}

// blocks 0..255: G(t+1) = h2 @ C^T + d ; blocks 256..319: fc2 output for step t.
__global__ __launch_bounds__(256) void out_and_q(const _Float16* __restrict__ xh2,
                                                 const _Float16* __restrict__ C_h,
                                                 const float* __restrict__ d_f,
                                                 _Float16* __restrict__ G,
                                                 const _Float16* __restrict__ Wa, const float* __restrict__ ab,
                                                 const _Float16* __restrict__ Wb, const float* __restrict__ bb,
                                                 const _Float16* __restrict__ Wc, const float* __restrict__ cb,
                                                 float* __restrict__ out, int t, int do_gemm) {
    __shared__ char smem[29696];   // max(q-gemm 18432, fc2 29440)
    if (blockIdx.x < 256) {
        if (!do_gemm) return;
        const int bm0 = (blockIdx.x >> 4) * 64, bn0 = (blockIdx.x & 15) * 64;
        f32x4 acc[4] = {};
        gemm_core_db<256, 64, 64, 64, 32, 32>(smem, xh2 + 512, 1024, C_h, 512, 512, bm0, bn0, acc);
        epi_plain<64, 64, 32, 32, 0>(acc, d_f, G, 1024, bm0, bn0);
    } else {
        fc2_mfma(smem, xh2, Wa, ab, Wb, bb, Wc, cb, out, (blockIdx.x - 256) * 16, t);
    }
}

// ---------------------------------------------------------------- launch
extern "C" void kernel_launch(void* const* d_in, const int* in_sizes, int n_in,
                              void* d_out, int out_size, void* d_ws, size_t ws_size,
                              hipStream_t stream) {
    const float* encoded = (const float*)d_in[0];
    const float* z       = (const float*)d_in[1];
    const float* q_w     = (const float*)d_in[2];
    const float* k_w     = (const float*)d_in[3];
    const float* v_w     = (const float*)d_in[4];
    const float* q_b     = (const float*)d_in[5];
    // d_in[6] (k_b): softmax-invariant — dropped exactly.
    const float* v_b     = (const float*)d_in[7];
    const float* out_w   = (const float*)d_in[8];
    const float* out_b   = (const float*)d_in[9];
    const float* fc1_w   = (const float*)d_in[10];
    const float* fc1_b   = (const float*)d_in[11];
    const float* l1_wih  = (const float*)d_in[12];
    const float* l1_whh  = (const float*)d_in[13];
    const float* l1_bih  = (const float*)d_in[14];
    const float* l1_bhh  = (const float*)d_in[15];
    const float* l2_wih  = (const float*)d_in[16];
    const float* l2_whh  = (const float*)d_in[17];
    const float* l2_bih  = (const float*)d_in[18];
    const float* l2_bhh  = (const float*)d_in[19];
    const float* fc2a_w  = (const float*)d_in[20];
    const float* fc2a_b  = (const float*)d_in[21];
    const float* fc2b_w  = (const float*)d_in[22];
    const float* fc2b_b  = (const float*)d_in[23];
    const float* fc2c_w  = (const float*)d_in[24];
    const float* fc2c_b  = (const float*)d_in[25];
    float* out = (float*)d_out;

    char* p = (char*)d_ws;
    auto take = [&](size_t bytes) { char* r = p; p += (bytes + 255) & ~(size_t)255; return r; };
    _Float16* encH  = (_Float16*)take(52428800);   // [1024,100,256] fp16
    _Float16* C_h   = (_Float16*)take(1048576);    // [1024,512]
    _Float16* Wfc1  = (_Float16*)take(1114112);    // [512,1088]
    _Float16* L1W   = (_Float16*)take(4194304);    // [2048,1024] rows h*4+g
    _Float16* L2W   = (_Float16*)take(4194304);
    _Float16* fc2a16= (_Float16*)take(262144);     // [256,512]
    _Float16* fc2b16= (_Float16*)take(65536);      // [128,256]
    _Float16* fc2c16= (_Float16*)take(512);        // [2,128]
    _Float16* eb    = (_Float16*)take(2228224);    // [1024,1088]
    char* zreg = p;                                // ---- zero region (10 MB) ----
    _Float16* xh1 = (_Float16*)take(2097152);      // [1024,1024] = [fc1out | h1]
    _Float16* xh2 = (_Float16*)take(2097152);      // [1024,1024] = [h1 | h2]
    _Float16* G   = (_Float16*)take(2097152);      // [1024,1024]
    float* c1     = (float*)take(2097152);
    float* c2     = (float*)take(2097152);         // ---- end zero region ----
    float* A      = (float*)take(1048576);
    float* d_f    = (float*)take(4096);
    _Float16* d_h = (_Float16*)take(2048);
    float* biasf  = (float*)take(2048);
    float* L1b    = (float*)take(8192);
    float* L2b    = (float*)take(8192);
    (void)in_sizes; (void)n_in; (void)out_size; (void)ws_size;

    zero_ws<<<2560, 256, 0, stream>>>((uint4*)zreg);
    conv_enc<<<25600, 256, 0, stream>>>((const float4*)encoded, (f16x4*)encH);
    prep_qk<<<1024, 256, 0, stream>>>(k_w, q_w, q_b, C_h, d_f, d_h);
    prep_A<<<512, 256, 0, stream>>>(fc1_w, out_w, A);
    prep_wfc1<<<512, 256, 0, stream>>>(A, v_w, v_b, fc1_w, out_b, fc1_b, Wfc1, biasf);
    prep_lstm<<<8192, 256, 0, stream>>>(l1_wih, l1_whh, l1_bih, l1_bhh, L1W, L1b);
    prep_lstm<<<8192, 256, 0, stream>>>(l2_wih, l2_whh, l2_bih, l2_bhh, L2W, L2b);
    prep_fc2c<<<641, 256, 0, stream>>>(fc2a_w, fc2b_w, fc2c_w, fc2a16, fc2b16, fc2c16);
    bcast_G<<<1024, 256, 0, stream>>>(d_h, G);

    for (int t = 0; t < TT; ++t) {
        attn_step<<<1024, 256, 0, stream>>>(G, encH, z, eb, t);
        // fc1: [1024,1088] @ [512,1088]^T, lrelu -> xh1[:, :512]
        gemm_k<256, 64, 32, 64, 16, 32, 1><<<dim3(16, 16), 256, 0, stream>>>(
            eb, 1088, Wfc1, 1088, biasf, xh1, 1024, 1088);
        // LSTM1: gates GEMM + fused ew -> h1 (xh1[:,512:], xh2[:,:512]), c1
        gemm_lstm<true><<<dim3(16, 16), 512, 0, stream>>>(xh1, L1W, L1b, c1, xh1 + 512, xh2);
        // LSTM2 -> h2 (xh2[:,512:]), c2
        gemm_lstm<false><<<dim3(16, 16), 512, 0, stream>>>(xh2, L2W, L2b, c2, xh2 + 512, nullptr);
        // fc2 output for step t + q-projection GEMM for step t+1
        out_and_q<<<320, 256, 0, stream>>>(xh2, C_h, d_f, G,
                                           fc2a16, fc2a_b, fc2b16, fc2b_b, fc2c16, fc2c_b,
                                           out, t, (t < TT - 1) ? 1 : 0);
    }
}